// Round 1
// baseline (67.554 us; speedup 1.0000x reference)
//
#include <hip/hip_runtime.h>

// ---------------------------------------------------------------------------
// LMU fused cell on MI355X (gfx950), bf16 MFMA.
//   inputs (f32): x(16384,128) h(16384,512) m(16384,256)
//                 Wx(512,128) Wh(512,512) Wm(512,256)
//                 ex(1,128) eh(1,512) em(1,256) AT(256,256) BT(256,1)
//   out (f32): new_h (16384*512) then new_m (16384*256), concatenated.
// Strategy: prologue packs all weights to bf16 in MFMA-B fragment layout in
// d_ws; one fused kernel per 64 batch rows does u -> new_m -> new_h with all
// operands staged once in LDS (XOR-swizzled to avoid bank conflicts).
// ---------------------------------------------------------------------------

typedef __bf16 bf16;
typedef bf16  bf16x8 __attribute__((ext_vector_type(8)));
typedef bf16  bf16x4 __attribute__((ext_vector_type(4)));
typedef float f32x4  __attribute__((ext_vector_type(4)));
typedef unsigned short u16;

#define BATCH 16384
// ws layout (u16 elements)
#define WPACK_OFF 0         // 896*512 = 458752  (Wall^T packed [k/8][512][8])
#define ATPACK_OFF 458752   // 256*256 = 65536   (AT^T packed  [k/8][256][8])
#define EPACK_OFF  524288   // 896*16  = 14336   (e packed     [k/8][16][8], col0=e)
#define PACK_TOTAL 538624

// LDS byte offsets (main kernel)
#define XS 0                // 64 x 128 bf16, rowb=256
#define HS 16384            // 64 x 512 bf16, rowb=1024
#define MS 81920            // 64 x 256 bf16, rowb=512 (m, later overwritten by new_m)
#define UL 114688           // 64 f32 u values
#define SMEM_BYTES 114944

__device__ __forceinline__ u16 f2bf(float f) {
  unsigned u = __builtin_bit_cast(unsigned, f);
  u += 0x7FFFu + ((u >> 16) & 1u);   // RNE (finite inputs)
  return (u16)(u >> 16);
}

__device__ __forceinline__ int swz(int row, int cb) {
  return cb ^ ((row & 7) << 4);      // spreads 16 rows across banks, 2-way max
}

// ---------------- prologue: pack weights to bf16 fragment layout ----------
__global__ __launch_bounds__(256) void lmu_pack(
    const float* __restrict__ Wx, const float* __restrict__ Wh,
    const float* __restrict__ Wm, const float* __restrict__ ex,
    const float* __restrict__ eh, const float* __restrict__ em,
    const float* __restrict__ AT, u16* __restrict__ ws) {
  int i = blockIdx.x * 256 + threadIdx.x;
  if (i < 458752) {                       // Wall^T[k][n] = [Wx|Wh|Wm][n][k]
    int j = i & 7, rest = i >> 3;
    int n = rest & 511, kk = rest >> 9;
    int k = kk * 8 + j;
    float v = (k < 128) ? Wx[n * 128 + k]
            : (k < 640) ? Wh[n * 512 + (k - 128)]
                        : Wm[n * 256 + (k - 640)];
    ws[WPACK_OFF + i] = f2bf(v);
  } else if (i < 524288) {                // AT^T[k][d] = AT[d][k]
    int t = i - 458752;
    int j = t & 7, rest = t >> 3;
    int d = rest & 255, kk = rest >> 8;
    ws[i] = f2bf(AT[d * 256 + kk * 8 + j]);
  } else if (i < PACK_TOTAL) {            // e as 896x16 B-operand, col 0 only
    int t = i - 524288;
    int j = t & 7, rest = t >> 3;
    int c = rest & 15, kk = rest >> 4;
    int k = kk * 8 + j;
    float v = 0.f;
    if (c == 0)
      v = (k < 128) ? ex[k] : (k < 640) ? eh[k - 128] : em[k - 640];
    ws[i] = f2bf(v);
  }
}

// ---------------- fused main kernel ----------------------------------------
__global__ __launch_bounds__(512, 2) void lmu_fused(
    const float* __restrict__ x, const float* __restrict__ h,
    const float* __restrict__ m, const float* __restrict__ BT,
    const u16* __restrict__ ws, float* __restrict__ out) {
  __shared__ __align__(16) char smem[SMEM_BYTES];
  const int tid  = threadIdx.x;
  const int lane = tid & 63;
  const int w    = tid >> 6;      // wave id 0..7
  const int lm   = lane & 15;     // A-row / B-col / C-col within 16x16 tile
  const int kg   = lane >> 4;     // k-group 0..3 (8 k each)
  const int b0   = blockIdx.x * 64;

  const u16* wpack  = ws + WPACK_OFF;
  const u16* atpack = ws + ATPACK_OFF;
  const u16* epack  = ws + EPACK_OFF;

  // ---- Phase 1: stage x,h,m as bf16 into LDS (swizzled) ----
  {
    const float4* xg = (const float4*)(x + (size_t)b0 * 128);
#pragma unroll
    for (int it = 0; it < 4; ++it) {       // 64*32 float4
      int f = it * 512 + tid;
      int r = f >> 5, c4 = f & 31;
      float4 v = xg[f];
      bf16x4 b = {(bf16)v.x, (bf16)v.y, (bf16)v.z, (bf16)v.w};
      *(bf16x4*)(smem + XS + r * 256 + swz(r, c4 * 8)) = b;
    }
    const float4* hg = (const float4*)(h + (size_t)b0 * 512);
#pragma unroll
    for (int it = 0; it < 16; ++it) {      // 64*128 float4
      int f = it * 512 + tid;
      int r = f >> 7, c4 = f & 127;
      float4 v = hg[f];
      bf16x4 b = {(bf16)v.x, (bf16)v.y, (bf16)v.z, (bf16)v.w};
      *(bf16x4*)(smem + HS + r * 1024 + swz(r, c4 * 8)) = b;
    }
    const float4* mg = (const float4*)(m + (size_t)b0 * 256);
#pragma unroll
    for (int it = 0; it < 8; ++it) {       // 64*64 float4
      int f = it * 512 + tid;
      int r = f >> 6, c4 = f & 63;
      float4 v = mg[f];
      bf16x4 b = {(bf16)v.x, (bf16)v.y, (bf16)v.z, (bf16)v.w};
      *(bf16x4*)(smem + MS + r * 512 + swz(r, c4 * 8)) = b;
    }
  }
  __syncthreads();

  // ---- Phase 2: u = [x|h|m] . e  (waves 0..3, wave = M-tile) ----
  if (w < 4) {
    f32x4 acc = {0.f, 0.f, 0.f, 0.f};
    const int row = w * 16 + lm;
#pragma unroll
    for (int ks = 0; ks < 4; ++ks) {       // x segment, kglobal = ks*32
      bf16x8 a = *(const bf16x8*)(smem + XS + row * 256 + swz(row, (ks * 32 + kg * 8) * 2));
      bf16x8 b = *(const bf16x8*)(epack + (((ks * 4 + kg) * 16) + lm) * 8);
      acc = __builtin_amdgcn_mfma_f32_16x16x32_bf16(a, b, acc, 0, 0, 0);
    }
#pragma unroll
    for (int ks = 0; ks < 16; ++ks) {      // h segment, kglobal = 128 + ks*32
      bf16x8 a = *(const bf16x8*)(smem + HS + row * 1024 + swz(row, (ks * 32 + kg * 8) * 2));
      bf16x8 b = *(const bf16x8*)(epack + (((16 + ks * 4 + kg) * 16) + lm) * 8);
      acc = __builtin_amdgcn_mfma_f32_16x16x32_bf16(a, b, acc, 0, 0, 0);
    }
#pragma unroll
    for (int ks = 0; ks < 8; ++ks) {       // m segment, kglobal = 640 + ks*32
      bf16x8 a = *(const bf16x8*)(smem + MS + row * 512 + swz(row, (ks * 32 + kg * 8) * 2));
      bf16x8 b = *(const bf16x8*)(epack + (((80 + ks * 4 + kg) * 16) + lm) * 8);
      acc = __builtin_amdgcn_mfma_f32_16x16x32_bf16(a, b, acc, 0, 0, 0);
    }
    if (lm == 0) {                          // C: col=lane&15, row=kg*4+reg
      float* u = (float*)(smem + UL);
#pragma unroll
      for (int r2 = 0; r2 < 4; ++r2) u[w * 16 + kg * 4 + r2] = acc[r2];
    }
  }
  __syncthreads();

  // ---- Phase 3: new_m = m @ AT^T + u*BT  (wave w: cols w*32..w*32+31) ----
  {
    const float* u = (const float*)(smem + UL);
    const int c0 = w * 32 + lm;
    float bt0 = BT[c0], bt1 = BT[c0 + 16];
    f32x4 accm[4][2];
#pragma unroll
    for (int mt = 0; mt < 4; ++mt)
#pragma unroll
      for (int r2 = 0; r2 < 4; ++r2) {
        float uv = u[mt * 16 + kg * 4 + r2];
        accm[mt][0][r2] = uv * bt0;
        accm[mt][1][r2] = uv * bt1;
      }
#pragma unroll
    for (int ks = 0; ks < 8; ++ks) {
      bf16x8 a[4];
#pragma unroll
      for (int mt = 0; mt < 4; ++mt) {
        int row = mt * 16 + lm;
        a[mt] = *(const bf16x8*)(smem + MS + row * 512 + swz(row, (ks * 32 + kg * 8) * 2));
      }
#pragma unroll
      for (int ct = 0; ct < 2; ++ct) {
        bf16x8 b = *(const bf16x8*)(atpack + (((ks * 4 + kg) * 256) + c0 + ct * 16) * 8);
#pragma unroll
        for (int mt = 0; mt < 4; ++mt)
          accm[mt][ct] = __builtin_amdgcn_mfma_f32_16x16x32_bf16(a[mt], b, accm[mt][ct], 0, 0, 0);
      }
    }
    // store new_m (f32) to out
    float* outm = out + (size_t)BATCH * 512;
#pragma unroll
    for (int mt = 0; mt < 4; ++mt)
#pragma unroll
      for (int r2 = 0; r2 < 4; ++r2) {
        size_t row = (size_t)(b0 + mt * 16 + kg * 4 + r2);
        outm[row * 256 + c0]      = accm[mt][0][r2];
        outm[row * 256 + c0 + 16] = accm[mt][1][r2];
      }
    __syncthreads();   // all reads of m done -> safe to overwrite MS
    // write bf16 new_m into MS
#pragma unroll
    for (int mt = 0; mt < 4; ++mt)
#pragma unroll
      for (int r2 = 0; r2 < 4; ++r2) {
        int rr = mt * 16 + kg * 4 + r2;
        *(bf16*)(smem + MS + rr * 512 + swz(rr, c0 * 2))        = (bf16)accm[mt][0][r2];
        *(bf16*)(smem + MS + rr * 512 + swz(rr, (c0 + 16) * 2)) = (bf16)accm[mt][1][r2];
      }
  }
  __syncthreads();

  // ---- Phase 4: new_h = sigmoid([x|h|new_m] @ Wall^T) ----
  {
    f32x4 acc[4][4];
    const f32x4 vzero = {0.f, 0.f, 0.f, 0.f};
#pragma unroll
    for (int mt = 0; mt < 4; ++mt)
#pragma unroll
      for (int ct = 0; ct < 4; ++ct) acc[mt][ct] = vzero;
    const int cb = w * 64 + lm;     // wave w owns cols w*64..w*64+63

    auto step = [&](int base, int rowb, int klocal, int kkg) {
      bf16x8 a[4];
#pragma unroll
      for (int mt = 0; mt < 4; ++mt) {
        int row = mt * 16 + lm;
        a[mt] = *(const bf16x8*)(smem + base + row * rowb + swz(row, (klocal + kg * 8) * 2));
      }
#pragma unroll
      for (int ct = 0; ct < 4; ++ct) {
        bf16x8 b = *(const bf16x8*)(wpack + (((kkg + kg) * 512) + cb + ct * 16) * 8);
#pragma unroll
        for (int mt = 0; mt < 4; ++mt)
          acc[mt][ct] = __builtin_amdgcn_mfma_f32_16x16x32_bf16(a[mt], b, acc[mt][ct], 0, 0, 0);
      }
    };
#pragma unroll
    for (int ks = 0; ks < 4; ++ks)  step(XS, 256,  ks * 32, ks * 4);        // k 0..127
#pragma unroll
    for (int ks = 0; ks < 16; ++ks) step(HS, 1024, ks * 32, 16 + ks * 4);   // k 128..639
#pragma unroll
    for (int ks = 0; ks < 8; ++ks)  step(MS, 512,  ks * 32, 80 + ks * 4);   // k 640..895

    // epilogue: sigmoid + store new_h
#pragma unroll
    for (int mt = 0; mt < 4; ++mt)
#pragma unroll
      for (int r2 = 0; r2 < 4; ++r2) {
        size_t row = (size_t)(b0 + mt * 16 + kg * 4 + r2);
#pragma unroll
        for (int ct = 0; ct < 4; ++ct) {
          float v = acc[mt][ct][r2];
          out[row * 512 + cb + ct * 16] = 1.0f / (1.0f + __expf(-v));
        }
      }
  }
}

extern "C" void kernel_launch(void* const* d_in, const int* in_sizes, int n_in,
                              void* d_out, int out_size, void* d_ws, size_t ws_size,
                              hipStream_t stream) {
  const float* x  = (const float*)d_in[0];
  const float* h  = (const float*)d_in[1];
  const float* m  = (const float*)d_in[2];
  const float* Wx = (const float*)d_in[3];
  const float* Wh = (const float*)d_in[4];
  const float* Wm = (const float*)d_in[5];
  const float* ex = (const float*)d_in[6];
  const float* eh = (const float*)d_in[7];
  const float* em = (const float*)d_in[8];
  const float* AT = (const float*)d_in[9];
  const float* BT = (const float*)d_in[10];
  float* out = (float*)d_out;
  u16* ws = (u16*)d_ws;   // needs 1,077,248 bytes

  lmu_pack<<<PACK_TOTAL / 256, 256, 0, stream>>>(Wx, Wh, Wm, ex, eh, em, AT, ws);
  lmu_fused<<<BATCH / 64, 512, 0, stream>>>(x, h, m, BT, ws, out);
}

// Round 2
// 64.234 us; speedup vs baseline: 1.0517x; 1.0517x over previous
//
#include <hip/hip_runtime.h>

// ---------------------------------------------------------------------------
// LMU fused cell on MI355X (gfx950), bf16 MFMA.  Round 2: BM=32, 2 blocks/CU.
//   inputs (f32): x(16384,128) h(16384,512) m(16384,256)
//                 Wx(512,128) Wh(512,512) Wm(512,256)
//                 ex(1,128) eh(1,512) em(1,256) AT(256,256) BT(256,1)
//   out (f32): new_h (16384*512) then new_m (16384*256), concatenated.
// Changes vs R1: 32-row blocks (LDS 57.5KB -> 2 blocks/CU for cross-block
// phase overlap), u computed by all 512 threads on the VALU (no MFMA, no
// epack), __launch_bounds__(512,4).
// ---------------------------------------------------------------------------

typedef __bf16 bf16;
typedef bf16  bf16x8 __attribute__((ext_vector_type(8)));
typedef bf16  bf16x4 __attribute__((ext_vector_type(4)));
typedef float f32x4  __attribute__((ext_vector_type(4)));
typedef unsigned short u16;

#define BATCH 16384
#define BM 32
// ws layout (u16 elements)
#define WPACK_OFF 0         // 896*512 = 458752  (Wall^T packed [k/8][512][8])
#define ATPACK_OFF 458752   // 256*256 = 65536   (AT^T packed  [k/8][256][8])
#define PACK_TOTAL 524288

// LDS byte offsets
#define XS 0                // 32 x 128 bf16, rowb=256
#define HS 8192             // 32 x 512 bf16, rowb=1024
#define MS 40960            // 32 x 256 bf16, rowb=512 (m, later new_m)
#define UL 57344            // 32 f32 u values
#define SMEM_BYTES 57472

__device__ __forceinline__ u16 f2bf(float f) {
  unsigned u = __builtin_bit_cast(unsigned, f);
  u += 0x7FFFu + ((u >> 16) & 1u);   // RNE (finite inputs)
  return (u16)(u >> 16);
}

__device__ __forceinline__ int swz(int row, int cb) {
  return cb ^ ((row & 7) << 4);
}

// ---------------- prologue: pack weights to bf16 fragment layout ----------
__global__ __launch_bounds__(256) void lmu_pack(
    const float* __restrict__ Wx, const float* __restrict__ Wh,
    const float* __restrict__ Wm, const float* __restrict__ AT,
    u16* __restrict__ ws) {
  int i = blockIdx.x * 256 + threadIdx.x;
  if (i < 458752) {                       // Wall^T[k][n] = [Wx|Wh|Wm][n][k]
    int j = i & 7, rest = i >> 3;
    int n = rest & 511, kk = rest >> 9;
    int k = kk * 8 + j;
    float v = (k < 128) ? Wx[n * 128 + k]
            : (k < 640) ? Wh[n * 512 + (k - 128)]
                        : Wm[n * 256 + (k - 640)];
    ws[WPACK_OFF + i] = f2bf(v);
  } else if (i < PACK_TOTAL) {            // AT^T[k][d] = AT[d][k]
    int t = i - 458752;
    int j = t & 7, rest = t >> 3;
    int d = rest & 255, kk = rest >> 8;
    ws[i] = f2bf(AT[d * 256 + kk * 8 + j]);
  }
}

// ---------------- fused main kernel ----------------------------------------
__global__ __launch_bounds__(512, 4) void lmu_fused(
    const float* __restrict__ x, const float* __restrict__ h,
    const float* __restrict__ m, const float* __restrict__ ex,
    const float* __restrict__ eh, const float* __restrict__ em,
    const float* __restrict__ BT, const u16* __restrict__ ws,
    float* __restrict__ out) {
  __shared__ __align__(16) char smem[SMEM_BYTES];
  const int tid  = threadIdx.x;
  const int lane = tid & 63;
  const int w    = tid >> 6;      // wave id 0..7
  const int lm   = lane & 15;     // A-row / B-col / C-col within 16x16 tile
  const int kg   = lane >> 4;     // k-group 0..3 (8 k each)
  const int b0   = blockIdx.x * BM;

  const u16* wpack  = ws + WPACK_OFF;
  const u16* atpack = ws + ATPACK_OFF;

  // ---- Phase 1: stage x,h,m as bf16 into LDS (swizzled) ----
  {
    const float4* xg = (const float4*)(x + (size_t)b0 * 128);
#pragma unroll
    for (int it = 0; it < 2; ++it) {       // 32*32 float4
      int f = it * 512 + tid;
      int r = f >> 5, c4 = f & 31;
      float4 v = xg[f];
      bf16x4 b = {(bf16)v.x, (bf16)v.y, (bf16)v.z, (bf16)v.w};
      *(bf16x4*)(smem + XS + r * 256 + swz(r, c4 * 8)) = b;
    }
    const float4* hg = (const float4*)(h + (size_t)b0 * 512);
#pragma unroll
    for (int it = 0; it < 8; ++it) {       // 32*128 float4
      int f = it * 512 + tid;
      int r = f >> 7, c4 = f & 127;
      float4 v = hg[f];
      bf16x4 b = {(bf16)v.x, (bf16)v.y, (bf16)v.z, (bf16)v.w};
      *(bf16x4*)(smem + HS + r * 1024 + swz(r, c4 * 8)) = b;
    }
    const float4* mg = (const float4*)(m + (size_t)b0 * 256);
#pragma unroll
    for (int it = 0; it < 4; ++it) {       // 32*64 float4
      int f = it * 512 + tid;
      int r = f >> 6, c4 = f & 63;
      float4 v = mg[f];
      bf16x4 b = {(bf16)v.x, (bf16)v.y, (bf16)v.z, (bf16)v.w};
      *(bf16x4*)(smem + MS + r * 512 + swz(r, c4 * 8)) = b;
    }
  }
  __syncthreads();

  // ---- Phase 2: u = [x|h|m] . e  (all 512 threads, VALU dot) ----
  {
    const int row = tid >> 4;       // 0..31
    const int q   = tid & 15;       // k-chunk 0..15, 56 elems each
    float s = 0.f;
#pragma unroll
    for (int j = 0; j < 7; ++j) {
      int k = q * 56 + j * 8;
      int base, rowb, klocal;
      const float* ep;
      if (k < 128)      { base = XS; rowb = 256;  klocal = k;       ep = ex + k; }
      else if (k < 640) { base = HS; rowb = 1024; klocal = k - 128; ep = eh + (k - 128); }
      else              { base = MS; rowb = 512;  klocal = k - 640; ep = em + (k - 640); }
      bf16x8 a = *(const bf16x8*)(smem + base + row * rowb + swz(row, klocal * 2));
      float4 e0 = *(const float4*)ep;
      float4 e1 = *(const float4*)(ep + 4);
      s += (float)a[0] * e0.x + (float)a[1] * e0.y + (float)a[2] * e0.z + (float)a[3] * e0.w;
      s += (float)a[4] * e1.x + (float)a[5] * e1.y + (float)a[6] * e1.z + (float)a[7] * e1.w;
    }
    s += __shfl_xor(s, 1);
    s += __shfl_xor(s, 2);
    s += __shfl_xor(s, 4);
    s += __shfl_xor(s, 8);
    if (q == 0) ((float*)(smem + UL))[row] = s;
  }
  __syncthreads();

  // ---- Phase 3: new_m = m @ AT^T + u*BT  (wave w: cols w*32..w*32+31) ----
  {
    const float* u = (const float*)(smem + UL);
    const int c0 = w * 32 + lm;
    float bt0 = BT[c0], bt1 = BT[c0 + 16];
    f32x4 accm[2][2];
#pragma unroll
    for (int mt = 0; mt < 2; ++mt)
#pragma unroll
      for (int r2 = 0; r2 < 4; ++r2) {
        float uv = u[mt * 16 + kg * 4 + r2];
        accm[mt][0][r2] = uv * bt0;
        accm[mt][1][r2] = uv * bt1;
      }
#pragma unroll
    for (int ks = 0; ks < 8; ++ks) {
      bf16x8 a[2];
#pragma unroll
      for (int mt = 0; mt < 2; ++mt) {
        int row = mt * 16 + lm;
        a[mt] = *(const bf16x8*)(smem + MS + row * 512 + swz(row, (ks * 32 + kg * 8) * 2));
      }
#pragma unroll
      for (int ct = 0; ct < 2; ++ct) {
        bf16x8 b = *(const bf16x8*)(atpack + (((ks * 4 + kg) * 256) + c0 + ct * 16) * 8);
#pragma unroll
        for (int mt = 0; mt < 2; ++mt)
          accm[mt][ct] = __builtin_amdgcn_mfma_f32_16x16x32_bf16(a[mt], b, accm[mt][ct], 0, 0, 0);
      }
    }
    // store new_m (f32) to out
    float* outm = out + (size_t)BATCH * 512;
#pragma unroll
    for (int mt = 0; mt < 2; ++mt)
#pragma unroll
      for (int r2 = 0; r2 < 4; ++r2) {
        size_t row = (size_t)(b0 + mt * 16 + kg * 4 + r2);
        outm[row * 256 + c0]      = accm[mt][0][r2];
        outm[row * 256 + c0 + 16] = accm[mt][1][r2];
      }
    __syncthreads();   // all reads of m done -> safe to overwrite MS
    // write bf16 new_m into MS
#pragma unroll
    for (int mt = 0; mt < 2; ++mt)
#pragma unroll
      for (int r2 = 0; r2 < 4; ++r2) {
        int rr = mt * 16 + kg * 4 + r2;
        *(bf16*)(smem + MS + rr * 512 + swz(rr, c0 * 2))        = (bf16)accm[mt][0][r2];
        *(bf16*)(smem + MS + rr * 512 + swz(rr, (c0 + 16) * 2)) = (bf16)accm[mt][1][r2];
      }
  }
  __syncthreads();

  // ---- Phase 4: new_h = sigmoid([x|h|new_m] @ Wall^T) ----
  {
    f32x4 acc[2][4];
    const f32x4 vzero = {0.f, 0.f, 0.f, 0.f};
#pragma unroll
    for (int mt = 0; mt < 2; ++mt)
#pragma unroll
      for (int ct = 0; ct < 4; ++ct) acc[mt][ct] = vzero;
    const int cb = w * 64 + lm;     // wave w owns cols w*64..w*64+63

    auto step = [&](int base, int rowb, int klocal, int kkg) {
      bf16x8 a[2];
#pragma unroll
      for (int mt = 0; mt < 2; ++mt) {
        int row = mt * 16 + lm;
        a[mt] = *(const bf16x8*)(smem + base + row * rowb + swz(row, (klocal + kg * 8) * 2));
      }
#pragma unroll
      for (int ct = 0; ct < 4; ++ct) {
        bf16x8 b = *(const bf16x8*)(wpack + (((kkg + kg) * 512) + cb + ct * 16) * 8);
#pragma unroll
        for (int mt = 0; mt < 2; ++mt)
          acc[mt][ct] = __builtin_amdgcn_mfma_f32_16x16x32_bf16(a[mt], b, acc[mt][ct], 0, 0, 0);
      }
    };
#pragma unroll
    for (int ks = 0; ks < 4; ++ks)  step(XS, 256,  ks * 32, ks * 4);        // k 0..127
#pragma unroll
    for (int ks = 0; ks < 16; ++ks) step(HS, 1024, ks * 32, 16 + ks * 4);   // k 128..639
#pragma unroll
    for (int ks = 0; ks < 8; ++ks)  step(MS, 512,  ks * 32, 80 + ks * 4);   // k 640..895

    // epilogue: sigmoid + store new_h
#pragma unroll
    for (int mt = 0; mt < 2; ++mt)
#pragma unroll
      for (int r2 = 0; r2 < 4; ++r2) {
        size_t row = (size_t)(b0 + mt * 16 + kg * 4 + r2);
#pragma unroll
        for (int ct = 0; ct < 4; ++ct) {
          float v = acc[mt][ct][r2];
          out[row * 512 + cb + ct * 16] = 1.0f / (1.0f + __expf(-v));
        }
      }
  }
}

extern "C" void kernel_launch(void* const* d_in, const int* in_sizes, int n_in,
                              void* d_out, int out_size, void* d_ws, size_t ws_size,
                              hipStream_t stream) {
  const float* x  = (const float*)d_in[0];
  const float* h  = (const float*)d_in[1];
  const float* m  = (const float*)d_in[2];
  const float* Wx = (const float*)d_in[3];
  const float* Wh = (const float*)d_in[4];
  const float* Wm = (const float*)d_in[5];
  const float* ex = (const float*)d_in[6];
  const float* eh = (const float*)d_in[7];
  const float* em = (const float*)d_in[8];
  const float* AT = (const float*)d_in[9];
  const float* BT = (const float*)d_in[10];
  float* out = (float*)d_out;
  u16* ws = (u16*)d_ws;   // needs 1,048,576 bytes

  lmu_pack<<<PACK_TOTAL / 256, 256, 0, stream>>>(Wx, Wh, Wm, AT, ws);
  lmu_fused<<<BATCH / BM, 512, 0, stream>>>(x, h, m, ex, eh, em, BT, ws, out);
}